// Round 1
// baseline (116.098 us; speedup 1.0000x reference)
//
#include <hip/hip_runtime.h>
#include <hip/hip_bf16.h>

#define NR 8192
#define DIM 512
#define BM 128
#define BN 128
#define BK 64

typedef __attribute__((ext_vector_type(8))) short bf16x8;
typedef __attribute__((ext_vector_type(4))) float f32x4;

__device__ static inline void gload_lds16(const void* g, void* l) {
    __builtin_amdgcn_global_load_lds(
        (const __attribute__((address_space(1))) void*)g,
        (__attribute__((address_space(3))) void*)l, 16, 0, 0);
}

// One block (256 threads) per row: compute |im|^2, |s|^2, im.s in one pass,
// write bf16-normalized rows + fp32 diag. Block 0 also zeroes the accumulator.
__global__ __launch_bounds__(256) void normalize_kernel(
    const float* __restrict__ im, const float* __restrict__ s,
    __hip_bfloat16* __restrict__ im_n, __hip_bfloat16* __restrict__ s_n,
    float* __restrict__ diag, double* __restrict__ acc)
{
    const int row = blockIdx.x;
    const int t = threadIdx.x;
    if (row == 0 && t == 0) acc[0] = 0.0;

    const float2* imr = (const float2*)(im + (size_t)row * DIM);
    const float2* sr  = (const float2*)(s  + (size_t)row * DIM);
    float2 iv = imr[t];
    float2 sv = sr[t];

    float sim = iv.x * iv.x + iv.y * iv.y;
    float sss = sv.x * sv.x + sv.y * sv.y;
    float sd  = iv.x * sv.x + iv.y * sv.y;

    #pragma unroll
    for (int off = 32; off; off >>= 1) {
        sim += __shfl_down(sim, off);
        sss += __shfl_down(sss, off);
        sd  += __shfl_down(sd, off);
    }

    __shared__ float red[3][4];
    const int wid = t >> 6, lane = t & 63;
    if (lane == 0) { red[0][wid] = sim; red[1][wid] = sss; red[2][wid] = sd; }
    __syncthreads();
    sim = red[0][0] + red[0][1] + red[0][2] + red[0][3];
    sss = red[1][0] + red[1][1] + red[1][2] + red[1][3];
    sd  = red[2][0] + red[2][1] + red[2][2] + red[2][3];

    const float ri = rsqrtf(sim);
    const float rs = rsqrtf(sss);
    if (t == 0) diag[row] = sd * ri * rs;

    __hip_bfloat162* io = (__hip_bfloat162*)(im_n + (size_t)row * DIM);
    __hip_bfloat162* so = (__hip_bfloat162*)(s_n  + (size_t)row * DIM);
    __hip_bfloat162 a, b;
    a.x = __float2bfloat16(iv.x * ri); a.y = __float2bfloat16(iv.y * ri);
    b.x = __float2bfloat16(sv.x * rs); b.y = __float2bfloat16(sv.y * rs);
    io[t] = a;
    so[t] = b;
}

// 128x128 tile bf16 MFMA GEMM (scores = A @ B^T), fused ranking-loss epilogue.
// LDS layout: [128 rows][8 chunks of 16B], chunk XOR-swizzled by (row&7) so
// both global_load_lds staging (linear dest, pre-swizzled global src) and
// ds_read_b128 fragment reads are bank-spread.
__global__ __launch_bounds__(256) void gemm_loss_kernel(
    const __hip_bfloat16* __restrict__ A,
    const __hip_bfloat16* __restrict__ B,
    const float* __restrict__ diag,
    double* __restrict__ acc_out)
{
    __shared__ char Asm[BM * BK * 2];   // 16 KB
    __shared__ char Bsm[BN * BK * 2];   // 16 KB
    __shared__ float part[4];

    const int tid  = threadIdx.x;
    const int lane = tid & 63;
    const int w    = tid >> 6;          // wave 0..3
    const int wr   = w >> 1, wc = w & 1;
    const int bm = blockIdx.y, bn = blockIdx.x;

    const int lr = lane >> 3;           // 0..7: row within 8-row group
    const int ls = lane & 7;            // 0..7: 16B slot
    const int chunk_sw = ls ^ lr;       // content chunk for swizzled store

    f32x4 zero = {0.f, 0.f, 0.f, 0.f};
    f32x4 acc[4][4];
    #pragma unroll
    for (int i = 0; i < 4; ++i)
        #pragma unroll
        for (int j = 0; j < 4; ++j) acc[i][j] = zero;

    const int frow = lane & 15;         // fragment row/col
    const int fc   = lane >> 4;         // 0..3: k-chunk within MFMA

    for (int kk = 0; kk < DIM / BK; ++kk) {
        const int k0 = kk * BK;
        #pragma unroll
        for (int q = 0; q < 4; ++q) {
            const int trow = (w * 4 + q) * 8 + lr;        // tile row 0..127
            const size_t ga = (size_t)(bm * BM + trow) * DIM + k0 + chunk_sw * 8;
            const size_t gb = (size_t)(bn * BN + trow) * DIM + k0 + chunk_sw * 8;
            gload_lds16(A + ga, Asm + (w * 4 + q) * 1024);
            gload_lds16(B + gb, Bsm + (w * 4 + q) * 1024);
        }
        __syncthreads();   // compiler drains vmcnt before barrier

        #pragma unroll
        for (int k2 = 0; k2 < 2; ++k2) {
            bf16x8 af[4], bfr[4];
            const int c = k2 * 4 + fc;
            #pragma unroll
            for (int mi = 0; mi < 4; ++mi) {
                const int row = wr * 64 + mi * 16 + frow;
                af[mi] = *(const bf16x8*)(Asm + row * 128 + ((c ^ (row & 7)) << 4));
            }
            #pragma unroll
            for (int ni = 0; ni < 4; ++ni) {
                const int row = wc * 64 + ni * 16 + frow;
                bfr[ni] = *(const bf16x8*)(Bsm + row * 128 + ((c ^ (row & 7)) << 4));
            }
            #pragma unroll
            for (int mi = 0; mi < 4; ++mi)
                #pragma unroll
                for (int ni = 0; ni < 4; ++ni)
                    acc[mi][ni] = __builtin_amdgcn_mfma_f32_16x16x32_bf16(
                        af[mi], bfr[ni], acc[mi][ni], 0, 0, 0);
        }
        __syncthreads();
    }

    // Fused epilogue: relu(1 - diag[col] + sc) + relu(1 - diag[row] + sc),
    // skip row==col. C/D layout: col = lane&15, row = (lane>>4)*4 + reg.
    float lsum = 0.f;
    #pragma unroll
    for (int mi = 0; mi < 4; ++mi) {
        const int rowbase = bm * BM + wr * 64 + mi * 16 + fc * 4;
        float dr[4];
        #pragma unroll
        for (int r = 0; r < 4; ++r) dr[r] = diag[rowbase + r];
        #pragma unroll
        for (int ni = 0; ni < 4; ++ni) {
            const int col = bn * BN + wc * 64 + ni * 16 + frow;
            const float dc = diag[col];
            #pragma unroll
            for (int r = 0; r < 4; ++r) {
                if (rowbase + r != col) {
                    const float sc = acc[mi][ni][r];
                    lsum += fmaxf(0.f, 1.0f - dc + sc)
                          + fmaxf(0.f, 1.0f - dr[r] + sc);
                }
            }
        }
    }
    #pragma unroll
    for (int off = 32; off; off >>= 1) lsum += __shfl_down(lsum, off);
    if (lane == 0) part[w] = lsum;
    __syncthreads();
    if (tid == 0) atomicAdd(acc_out, (double)(part[0] + part[1] + part[2] + part[3]));
}

__global__ void finalize_kernel(const double* __restrict__ acc, float* __restrict__ out)
{
    out[0] = (float)(acc[0] * (1.0 / (double)NR));
}

extern "C" void kernel_launch(void* const* d_in, const int* in_sizes, int n_in,
                              void* d_out, int out_size, void* d_ws, size_t ws_size,
                              hipStream_t stream)
{
    const float* im = (const float*)d_in[0];
    const float* s  = (const float*)d_in[1];

    char* ws = (char*)d_ws;
    __hip_bfloat16* im_n = (__hip_bfloat16*)ws;                               // 8 MB
    __hip_bfloat16* s_n  = (__hip_bfloat16*)(ws + (size_t)NR * DIM * 2);      // 8 MB
    float* diag          = (float*)(ws + (size_t)NR * DIM * 4);               // 32 KB
    double* acc          = (double*)(ws + (size_t)NR * DIM * 4 + NR * 4);     // 8 B

    normalize_kernel<<<NR, 256, 0, stream>>>(im, s, im_n, s_n, diag, acc);

    dim3 grid(NR / BN, NR / BM);
    gemm_loss_kernel<<<grid, 256, 0, stream>>>(im_n, s_n, diag, acc);

    finalize_kernel<<<1, 1, 0, stream>>>(acc, (float*)d_out);
}

// Round 2
// 92.301 us; speedup vs baseline: 1.2578x; 1.2578x over previous
//
#include <hip/hip_runtime.h>
#include <hip/hip_bf16.h>

#define NR 8192
#define DIM 512

typedef __attribute__((ext_vector_type(8))) short bf16x8;
typedef __attribute__((ext_vector_type(4))) float f32x4;

__device__ static inline void gload_lds16(const void* g, void* l) {
    __builtin_amdgcn_global_load_lds(
        (const __attribute__((address_space(1))) void*)g,
        (__attribute__((address_space(3))) void*)l, 16, 0, 0);
}

// One block (256 threads) per row: compute |im|^2, |s|^2, im.s in one pass,
// write bf16-normalized rows + fp32 diag. Block 0 also zeroes the accumulator.
__global__ __launch_bounds__(256) void normalize_kernel(
    const float* __restrict__ im, const float* __restrict__ s,
    __hip_bfloat16* __restrict__ im_n, __hip_bfloat16* __restrict__ s_n,
    float* __restrict__ diag, double* __restrict__ acc)
{
    const int row = blockIdx.x;
    const int t = threadIdx.x;
    if (row == 0 && t == 0) acc[0] = 0.0;

    const float2* imr = (const float2*)(im + (size_t)row * DIM);
    const float2* sr  = (const float2*)(s  + (size_t)row * DIM);
    float2 iv = imr[t];
    float2 sv = sr[t];

    float sim = iv.x * iv.x + iv.y * iv.y;
    float sss = sv.x * sv.x + sv.y * sv.y;
    float sd  = iv.x * sv.x + iv.y * sv.y;

    #pragma unroll
    for (int off = 32; off; off >>= 1) {
        sim += __shfl_down(sim, off);
        sss += __shfl_down(sss, off);
        sd  += __shfl_down(sd, off);
    }

    __shared__ float red[3][4];
    const int wid = t >> 6, lane = t & 63;
    if (lane == 0) { red[0][wid] = sim; red[1][wid] = sss; red[2][wid] = sd; }
    __syncthreads();
    sim = red[0][0] + red[0][1] + red[0][2] + red[0][3];
    sss = red[1][0] + red[1][1] + red[1][2] + red[1][3];
    sd  = red[2][0] + red[2][1] + red[2][2] + red[2][3];

    const float ri = rsqrtf(sim);
    const float rs = rsqrtf(sss);
    if (t == 0) diag[row] = sd * ri * rs;

    __hip_bfloat162* io = (__hip_bfloat162*)(im_n + (size_t)row * DIM);
    __hip_bfloat162* so = (__hip_bfloat162*)(s_n  + (size_t)row * DIM);
    __hip_bfloat162 a, b;
    a.x = __float2bfloat16(iv.x * ri); a.y = __float2bfloat16(iv.y * ri);
    b.x = __float2bfloat16(sv.x * rs); b.y = __float2bfloat16(sv.y * rs);
    io[t] = a;
    so[t] = b;
}

// 256x256 tile, BK=64, 8 waves (2M x 4N), double-buffered LDS (128 KiB),
// 4-phase-per-K-tile pipelined schedule with counted vmcnt(4) (3 half-tiles
// in flight, never drained to 0 in the main loop). Per phase: stage one
// half-tile of K-tile t+1, ds_read one quadrant's frags, 16 MFMA (setprio-
// wrapped), s_waitcnt vmcnt(4) + s_barrier. Fused ranking-loss epilogue.
__global__ __launch_bounds__(512, 2) void gemm_loss_kernel(
    const __hip_bfloat16* __restrict__ A,
    const __hip_bfloat16* __restrict__ B,
    const float* __restrict__ diag,
    double* __restrict__ acc_out)
{
    __shared__ char Asm[2][32768];   // [buf][256 rows][128 B]
    __shared__ char Bsm[2][32768];

    const int tid  = threadIdx.x;
    const int l    = tid & 63;
    const int w    = tid >> 6;          // wave 0..7
    const int wm   = w >> 2;            // 0..1
    const int wn   = w & 3;             // 0..3
    const int bm = blockIdx.y, bn = blockIdx.x;

    const int lr = l >> 3;              // 0..7 row within 8-row group
    const int ls = l & 7;               // 0..7 16B slot
    const int csw = ls ^ lr;            // swizzled content chunk for staging

    const int frow = l & 15;            // fragment lane row (A/B row dim)
    const int fc   = l >> 4;            // 0..3 k-chunk

    const char* Agb = (const char*)A + (size_t)bm * 256 * (DIM * 2);
    const char* Bgb = (const char*)B + (size_t)bn * 256 * (DIM * 2);

    // -- staging: one half-tile (128 rows x 128 B) = 2 gload_lds/thread
    auto stageA = [&](int b, int h, int tt) {
        #pragma unroll
        for (int q = 0; q < 2; ++q) {
            const int rit = h * 128 + q * 64 + w * 8 + lr;
            gload_lds16(Agb + (size_t)rit * (DIM * 2) + tt * 128 + csw * 16,
                        &Asm[b][(h * 128 + q * 64 + w * 8) * 128]);
        }
    };
    auto stageB = [&](int b, int h, int tt) {
        #pragma unroll
        for (int q = 0; q < 2; ++q) {
            const int rit = h * 128 + q * 64 + w * 8 + lr;
            gload_lds16(Bgb + (size_t)rit * (DIM * 2) + tt * 128 + csw * 16,
                        &Bsm[b][(h * 128 + q * 64 + w * 8) * 128]);
        }
    };

    // -- LDS -> register fragments (swizzled read)
    auto ldA = [&](bf16x8 (&af)[4][2], int b, int qm) {
        #pragma unroll
        for (int mi = 0; mi < 4; ++mi) {
            const int row = qm * 128 + wm * 64 + mi * 16 + frow;
            const int rsw = (row & 7) << 4;
            #pragma unroll
            for (int k2 = 0; k2 < 2; ++k2)
                af[mi][k2] = *(const bf16x8*)&Asm[b][row * 128 + ((((k2 * 4 + fc) << 4)) ^ rsw)];
        }
    };
    auto ldB = [&](bf16x8 (&bfr)[2][2], int b, int qn) {
        #pragma unroll
        for (int ni = 0; ni < 2; ++ni) {
            const int row = qn * 128 + wn * 32 + ni * 16 + frow;
            const int rsw = (row & 7) << 4;
            #pragma unroll
            for (int k2 = 0; k2 < 2; ++k2)
                bfr[ni][k2] = *(const bf16x8*)&Bsm[b][row * 128 + ((((k2 * 4 + fc) << 4)) ^ rsw)];
        }
    };

    f32x4 acc00[4][2], acc01[4][2], acc11[4][2], acc10[4][2];
    f32x4 zero = {0.f, 0.f, 0.f, 0.f};
    #pragma unroll
    for (int mi = 0; mi < 4; ++mi)
        #pragma unroll
        for (int ni = 0; ni < 2; ++ni) {
            acc00[mi][ni] = zero; acc01[mi][ni] = zero;
            acc11[mi][ni] = zero; acc10[mi][ni] = zero;
        }

    auto mmaq = [&](f32x4 (&ac)[4][2], bf16x8 (&af)[4][2], bf16x8 (&bfr)[2][2]) {
        __builtin_amdgcn_s_setprio(1);
        #pragma unroll
        for (int k2 = 0; k2 < 2; ++k2)
            #pragma unroll
            for (int mi = 0; mi < 4; ++mi)
                #pragma unroll
                for (int ni = 0; ni < 2; ++ni)
                    ac[mi][ni] = __builtin_amdgcn_mfma_f32_16x16x32_bf16(
                        af[mi][k2], bfr[ni][k2], ac[mi][ni], 0, 0, 0);
        __builtin_amdgcn_s_setprio(0);
    };

    #define WAITBAR4 asm volatile("s_waitcnt vmcnt(4)\n\ts_barrier" ::: "memory")

    // -- prologue: stage K-tile 0 (order A0,B0,B1,A1); drain A0,B0
    stageA(0, 0, 0); stageB(0, 0, 0); stageB(0, 1, 0); stageA(0, 1, 0);
    WAITBAR4;

    bf16x8 af[4][2], bfr[2][2];

    // -- main loop: windows t=0..6, each stages K-tile t+1 into buf^1
    for (int t = 0; t < 7; ++t) {
        const int b = t & 1, nb = b ^ 1;
        // w1: quadrant (0,0)
        stageA(nb, 0, t + 1);
        ldA(af, b, 0); ldB(bfr, b, 0);
        mmaq(acc00, af, bfr);
        WAITBAR4;                      // drains B1(t)
        // w2: quadrant (0,1) — A held
        stageB(nb, 0, t + 1);
        ldB(bfr, b, 1);
        mmaq(acc01, af, bfr);
        WAITBAR4;                      // drains A1(t)
        // w3: quadrant (1,1) — B held
        stageB(nb, 1, t + 1);
        ldA(af, b, 1);
        mmaq(acc11, af, bfr);
        WAITBAR4;
        // w4: quadrant (1,0) — A held, B0 re-read
        stageA(nb, 1, t + 1);
        ldB(bfr, b, 0);
        mmaq(acc10, af, bfr);
        WAITBAR4;                      // drains A0(t+1),B0(t+1)
    }

    // -- last window (tile 7, buf 1): no staging; drain 4 -> 2 -> 0
    {
        ldA(af, 1, 0); ldB(bfr, 1, 0);
        mmaq(acc00, af, bfr);
        asm volatile("s_waitcnt vmcnt(2)\n\ts_barrier" ::: "memory");
        ldB(bfr, 1, 1);
        mmaq(acc01, af, bfr);
        asm volatile("s_waitcnt vmcnt(0)\n\ts_barrier" ::: "memory");
        ldA(af, 1, 1);
        mmaq(acc11, af, bfr);
        ldB(bfr, 1, 0);
        mmaq(acc10, af, bfr);
    }

    // -- fused epilogue: relu(1 - diag[col] + sc) + relu(1 - diag[row] + sc)
    float lsum = 0.f;
    const int rb0 = bm * 256 + wm * 64;
    const int cb0 = bn * 256 + wn * 32;
    auto sumq = [&](f32x4 (&ac)[4][2], int qm, int qn) {
        #pragma unroll
        for (int mi = 0; mi < 4; ++mi) {
            const int rowb = rb0 + qm * 128 + mi * 16 + fc * 4;
            float dr[4];
            #pragma unroll
            for (int r = 0; r < 4; ++r) dr[r] = diag[rowb + r];
            #pragma unroll
            for (int ni = 0; ni < 2; ++ni) {
                const int col = cb0 + qn * 128 + ni * 16 + frow;
                const float dc = diag[col];
                #pragma unroll
                for (int r = 0; r < 4; ++r) {
                    if (rowb + r != col) {
                        const float sc = ac[mi][ni][r];
                        lsum += fmaxf(0.f, 1.0f - dc + sc)
                              + fmaxf(0.f, 1.0f - dr[r] + sc);
                    }
                }
            }
        }
    };
    sumq(acc00, 0, 0); sumq(acc01, 0, 1); sumq(acc11, 1, 1); sumq(acc10, 1, 0);

    #pragma unroll
    for (int off = 32; off; off >>= 1) lsum += __shfl_down(lsum, off);

    float* part = (float*)&Asm[0][0];   // reuse LDS (all tile reads done)
    __syncthreads();
    if (l == 0) part[w] = lsum;
    __syncthreads();
    if (tid == 0) {
        float bs = 0.f;
        #pragma unroll
        for (int i = 0; i < 8; ++i) bs += part[i];
        atomicAdd(acc_out, (double)bs);
    }
}

__global__ void finalize_kernel(const double* __restrict__ acc, float* __restrict__ out)
{
    out[0] = (float)(acc[0] * (1.0 / (double)NR));
}

extern "C" void kernel_launch(void* const* d_in, const int* in_sizes, int n_in,
                              void* d_out, int out_size, void* d_ws, size_t ws_size,
                              hipStream_t stream)
{
    const float* im = (const float*)d_in[0];
    const float* s  = (const float*)d_in[1];

    char* ws = (char*)d_ws;
    __hip_bfloat16* im_n = (__hip_bfloat16*)ws;                               // 8 MB
    __hip_bfloat16* s_n  = (__hip_bfloat16*)(ws + (size_t)NR * DIM * 2);      // 8 MB
    float* diag          = (float*)(ws + (size_t)NR * DIM * 4);               // 32 KB
    double* acc          = (double*)(ws + (size_t)NR * DIM * 4 + NR * 4);     // 8 B

    normalize_kernel<<<NR, 256, 0, stream>>>(im, s, im_n, s_n, diag, acc);

    dim3 grid(NR / 256, NR / 256);
    gemm_loss_kernel<<<grid, 512, 0, stream>>>(im_n, s_n, diag, acc);

    finalize_kernel<<<1, 1, 0, stream>>>(acc, (float*)d_out);
}

// Round 3
// 90.191 us; speedup vs baseline: 1.2873x; 1.0234x over previous
//
#include <hip/hip_runtime.h>
#include <hip/hip_bf16.h>

#define NR 8192
#define DIM 512

typedef __attribute__((ext_vector_type(8))) short bf16x8;
typedef __attribute__((ext_vector_type(4))) float f32x4;

__device__ static inline void gload_lds16(const void* g, void* l) {
    __builtin_amdgcn_global_load_lds(
        (const __attribute__((address_space(1))) void*)g,
        (__attribute__((address_space(3))) void*)l, 16, 0, 0);
}

// One block (256 threads) per row: compute |im|^2, |s|^2, im.s in one pass,
// write bf16-normalized rows + fp32 diag. Block 0 also zeroes the accumulator.
__global__ __launch_bounds__(256) void normalize_kernel(
    const float* __restrict__ im, const float* __restrict__ s,
    __hip_bfloat16* __restrict__ im_n, __hip_bfloat16* __restrict__ s_n,
    float* __restrict__ diag, double* __restrict__ acc)
{
    const int row = blockIdx.x;
    const int t = threadIdx.x;
    if (row == 0 && t == 0) acc[0] = 0.0;

    const float2* imr = (const float2*)(im + (size_t)row * DIM);
    const float2* sr  = (const float2*)(s  + (size_t)row * DIM);
    float2 iv = imr[t];
    float2 sv = sr[t];

    float sim = iv.x * iv.x + iv.y * iv.y;
    float sss = sv.x * sv.x + sv.y * sv.y;
    float sd  = iv.x * sv.x + iv.y * sv.y;

    #pragma unroll
    for (int off = 32; off; off >>= 1) {
        sim += __shfl_down(sim, off);
        sss += __shfl_down(sss, off);
        sd  += __shfl_down(sd, off);
    }

    __shared__ float red[3][4];
    const int wid = t >> 6, lane = t & 63;
    if (lane == 0) { red[0][wid] = sim; red[1][wid] = sss; red[2][wid] = sd; }
    __syncthreads();
    sim = red[0][0] + red[0][1] + red[0][2] + red[0][3];
    sss = red[1][0] + red[1][1] + red[1][2] + red[1][3];
    sd  = red[2][0] + red[2][1] + red[2][2] + red[2][3];

    const float ri = rsqrtf(sim);
    const float rs = rsqrtf(sss);
    if (t == 0) diag[row] = sd * ri * rs;

    __hip_bfloat162* io = (__hip_bfloat162*)(im_n + (size_t)row * DIM);
    __hip_bfloat162* so = (__hip_bfloat162*)(s_n  + (size_t)row * DIM);
    __hip_bfloat162 a, b;
    a.x = __float2bfloat16(iv.x * ri); a.y = __float2bfloat16(iv.y * ri);
    b.x = __float2bfloat16(sv.x * rs); b.y = __float2bfloat16(sv.y * rs);
    io[t] = a;
    so[t] = b;
}

// 256x256 tile, BK=64, 8 waves (2M x 4N), double-buffered LDS (128 KiB).
// m201-style 8-phase schedule: per phase {ds_reads || stage half-tile ->
// s_waitcnt vmcnt(4) -> s_barrier -> lgkmcnt(0)+sched_barrier ->
// setprio(1) 16xMFMA setprio(0) -> s_barrier}. vmcnt never drained to 0
// in the main loop (steady state 6->4 outstanding; each drain >=2 phases
// after issue). B-half0 fragment held in registers p1->p4.
__global__ __launch_bounds__(512, 2) void gemm_loss_kernel(
    const __hip_bfloat16* __restrict__ A,
    const __hip_bfloat16* __restrict__ B,
    const float* __restrict__ diag,
    double* __restrict__ acc_out)
{
    __shared__ char Asm[2][32768];   // [buf][256 rows][128 B]
    __shared__ char Bsm[2][32768];

    const int tid  = threadIdx.x;
    const int l    = tid & 63;
    const int w    = tid >> 6;          // wave 0..7
    const int wm   = w >> 2;            // 0..1
    const int wn   = w & 3;             // 0..3
    const int bm = blockIdx.y, bn = blockIdx.x;

    const int lr = l >> 3;              // 0..7 row within 8-row group
    const int ls = l & 7;               // 0..7 16B slot
    const int csw = ls ^ lr;            // swizzled content chunk for staging

    const int frow = l & 15;            // fragment lane row
    const int fc   = l >> 4;            // 0..3 k-chunk

    const char* Agb = (const char*)A + (size_t)bm * 256 * (DIM * 2);
    const char* Bgb = (const char*)B + (size_t)bn * 256 * (DIM * 2);

    auto stageA = [&](int b, int h, int tt) {
        #pragma unroll
        for (int q = 0; q < 2; ++q) {
            const int rit = h * 128 + q * 64 + w * 8 + lr;
            gload_lds16(Agb + (size_t)rit * (DIM * 2) + tt * 128 + csw * 16,
                        &Asm[b][(h * 128 + q * 64 + w * 8) * 128]);
        }
    };
    auto stageB = [&](int b, int h, int tt) {
        #pragma unroll
        for (int q = 0; q < 2; ++q) {
            const int rit = h * 128 + q * 64 + w * 8 + lr;
            gload_lds16(Bgb + (size_t)rit * (DIM * 2) + tt * 128 + csw * 16,
                        &Bsm[b][(h * 128 + q * 64 + w * 8) * 128]);
        }
    };

    auto ldA = [&](bf16x8 (&af)[4][2], int b, int qm) {
        #pragma unroll
        for (int mi = 0; mi < 4; ++mi) {
            const int row = qm * 128 + wm * 64 + mi * 16 + frow;
            const int rsw = (row & 7) << 4;
            #pragma unroll
            for (int k2 = 0; k2 < 2; ++k2)
                af[mi][k2] = *(const bf16x8*)&Asm[b][row * 128 + ((((k2 * 4 + fc) << 4)) ^ rsw)];
        }
    };
    auto ldB = [&](bf16x8 (&bfr)[2][2], int b, int qn) {
        #pragma unroll
        for (int ni = 0; ni < 2; ++ni) {
            const int row = qn * 128 + wn * 32 + ni * 16 + frow;
            const int rsw = (row & 7) << 4;
            #pragma unroll
            for (int k2 = 0; k2 < 2; ++k2)
                bfr[ni][k2] = *(const bf16x8*)&Bsm[b][row * 128 + ((((k2 * 4 + fc) << 4)) ^ rsw)];
        }
    };

    f32x4 acc00[4][2], acc01[4][2], acc11[4][2], acc10[4][2];
    f32x4 zero = {0.f, 0.f, 0.f, 0.f};
    #pragma unroll
    for (int mi = 0; mi < 4; ++mi)
        #pragma unroll
        for (int ni = 0; ni < 2; ++ni) {
            acc00[mi][ni] = zero; acc01[mi][ni] = zero;
            acc11[mi][ni] = zero; acc10[mi][ni] = zero;
        }

    auto mmaq = [&](f32x4 (&ac)[4][2], bf16x8 (&af)[4][2], bf16x8 (&bfr)[2][2]) {
        __builtin_amdgcn_s_setprio(1);
        #pragma unroll
        for (int k2 = 0; k2 < 2; ++k2)
            #pragma unroll
            for (int mi = 0; mi < 4; ++mi)
                #pragma unroll
                for (int ni = 0; ni < 2; ++ni)
                    ac[mi][ni] = __builtin_amdgcn_mfma_f32_16x16x32_bf16(
                        af[mi][k2], bfr[ni][k2], ac[mi][ni], 0, 0, 0);
        __builtin_amdgcn_s_setprio(0);
    };

    #define BAR __builtin_amdgcn_s_barrier()
    #define LGKM0_FENCE do { \
        asm volatile("s_waitcnt lgkmcnt(0)" ::: "memory"); \
        __builtin_amdgcn_sched_barrier(0); } while (0)

    bf16x8 afA[4][2];     // current A-half fragments (A0 in p1-p2, A1 in p3-p4)
    bf16x8 bfr0[2][2];    // B-half0, held p1 -> p4
    bf16x8 bfrB[2][2];    // B-half1

    // ---- prologue: stage K-tile 0 (A0,B0,B1,A1); drain A0,B0 ----
    stageA(0, 0, 0); stageB(0, 0, 0); stageB(0, 1, 0); stageA(0, 1, 0);
    asm volatile("s_waitcnt vmcnt(4)" ::: "memory");
    BAR;

    // ---- main loop: tiles t=0..6, staging tile t+1 into buf^1 ----
    for (int t = 0; t < 7; ++t) {
        const int b = t & 1, nb = b ^ 1;

        // P1: quadrant (0,0) — 12 ds_reads, stage A0(t+1)
        ldA(afA, b, 0);
        ldB(bfr0, b, 0);
        stageA(nb, 0, t + 1);
        asm volatile("s_waitcnt vmcnt(4) lgkmcnt(8)" ::: "memory");  // drains B1(t)
        BAR;
        LGKM0_FENCE;
        mmaq(acc00, afA, bfr0);
        BAR;

        // P2: quadrant (0,1) — 4 ds_reads, stage B0(t+1)
        ldB(bfrB, b, 1);
        stageB(nb, 0, t + 1);
        asm volatile("s_waitcnt vmcnt(4)" ::: "memory");             // drains A1(t)
        BAR;
        LGKM0_FENCE;
        mmaq(acc01, afA, bfrB);
        BAR;

        // P3: quadrant (1,1) — 8 ds_reads, stage B1(t+1)
        ldA(afA, b, 1);
        stageB(nb, 1, t + 1);
        asm volatile("s_waitcnt vmcnt(4)" ::: "memory");             // drains A0(t+1)
        BAR;
        LGKM0_FENCE;
        mmaq(acc11, afA, bfrB);
        BAR;

        // P4: quadrant (1,0) — 0 ds_reads (B0 held), stage A1(t+1)
        stageA(nb, 1, t + 1);
        asm volatile("s_waitcnt vmcnt(4)" ::: "memory");             // drains B0(t+1)
        BAR;
        __builtin_amdgcn_sched_barrier(0);
        mmaq(acc10, afA, bfr0);
        BAR;
    }

    // ---- tail: tile 7 in buf 1, no staging; drain 4 -> 2 -> 0 ----
    {
        ldA(afA, 1, 0);
        ldB(bfr0, 1, 0);
        asm volatile("s_waitcnt vmcnt(2)" ::: "memory");             // drains B1(7)
        BAR;
        LGKM0_FENCE;
        mmaq(acc00, afA, bfr0);
        BAR;

        ldB(bfrB, 1, 1);
        asm volatile("s_waitcnt vmcnt(0)" ::: "memory");             // drains A1(7)
        BAR;
        LGKM0_FENCE;
        mmaq(acc01, afA, bfrB);
        BAR;

        ldA(afA, 1, 1);
        LGKM0_FENCE;
        mmaq(acc11, afA, bfrB);
        mmaq(acc10, afA, bfr0);
    }

    // ---- fused epilogue: relu(1 - diag[col] + sc) + relu(1 - diag[row] + sc)
    float lsum = 0.f;
    const int rb0 = bm * 256 + wm * 64;
    const int cb0 = bn * 256 + wn * 32;
    auto sumq = [&](f32x4 (&ac)[4][2], int qm, int qn) {
        #pragma unroll
        for (int mi = 0; mi < 4; ++mi) {
            const int rowb = rb0 + qm * 128 + mi * 16 + fc * 4;
            float dr[4];
            #pragma unroll
            for (int r = 0; r < 4; ++r) dr[r] = diag[rowb + r];
            #pragma unroll
            for (int ni = 0; ni < 2; ++ni) {
                const int col = cb0 + qn * 128 + ni * 16 + frow;
                const float dc = diag[col];
                #pragma unroll
                for (int r = 0; r < 4; ++r) {
                    if (rowb + r != col) {
                        const float sc = ac[mi][ni][r];
                        lsum += fmaxf(0.f, 1.0f - dc + sc)
                              + fmaxf(0.f, 1.0f - dr[r] + sc);
                    }
                }
            }
        }
    };
    sumq(acc00, 0, 0); sumq(acc01, 0, 1); sumq(acc11, 1, 1); sumq(acc10, 1, 0);

    #pragma unroll
    for (int off = 32; off; off >>= 1) lsum += __shfl_down(lsum, off);

    float* part = (float*)&Asm[0][0];   // reuse LDS (all tile reads done)
    __syncthreads();
    if (l == 0) part[w] = lsum;
    __syncthreads();
    if (tid == 0) {
        float bs = 0.f;
        #pragma unroll
        for (int i = 0; i < 8; ++i) bs += part[i];
        atomicAdd(acc_out, (double)bs);
    }
}

__global__ void finalize_kernel(const double* __restrict__ acc, float* __restrict__ out)
{
    out[0] = (float)(acc[0] * (1.0 / (double)NR));
}

extern "C" void kernel_launch(void* const* d_in, const int* in_sizes, int n_in,
                              void* d_out, int out_size, void* d_ws, size_t ws_size,
                              hipStream_t stream)
{
    const float* im = (const float*)d_in[0];
    const float* s  = (const float*)d_in[1];

    char* ws = (char*)d_ws;
    __hip_bfloat16* im_n = (__hip_bfloat16*)ws;                               // 8 MB
    __hip_bfloat16* s_n  = (__hip_bfloat16*)(ws + (size_t)NR * DIM * 2);      // 8 MB
    float* diag          = (float*)(ws + (size_t)NR * DIM * 4);               // 32 KB
    double* acc          = (double*)(ws + (size_t)NR * DIM * 4 + NR * 4);     // 8 B

    normalize_kernel<<<NR, 256, 0, stream>>>(im, s, im_n, s_n, diag, acc);

    dim3 grid(NR / 256, NR / 256);
    gemm_loss_kernel<<<grid, 512, 0, stream>>>(im_n, s_n, diag, acc);

    finalize_kernel<<<1, 1, 0, stream>>>(acc, (float*)d_out);
}